// Round 5
// baseline (452.679 us; speedup 1.0000x reference)
//
#include <hip/hip_runtime.h>

// ChannelAttentionModule (DANet channel attention) via bf16 MFMA.
// x: [B=8, C=512, N=96*96=9216] fp32, gamma scalar.
// v5: kill feat's 7.08M LDS bank-conflict cycles (16-way ds_write_b128 in the
// register B-transpose) by materializing Y^T bf16 once and DMA-staging feat's
// B tile via global_load_lds with XOR-swizzled source — identical to gram's
// conflict-free structure. Tiers: 216MB fused conv+transpose; 152MB separate
// transpose overlaid on dead part; 144MB = verified v4; else fp32 path.

typedef __attribute__((ext_vector_type(8))) short short8;   // 8 bf16 = 4 VGPR
typedef __attribute__((ext_vector_type(4))) float f32x4;    // MFMA C/D

#define GT 128      // gram/feat tile (M=N=128)
#define BK 64       // K-chunk (shorts)
#define LDA 72      // fp32-fallback LDS row stride (shorts)
#define NSPLIT 8    // gram split-K
#define FBSPLIT 4   // fallback gram split-K

__device__ inline unsigned short f2bf(float f) {            // RNE (softmax only)
    unsigned u = __builtin_bit_cast(unsigned, f);
    u += 0x7fffu + ((u >> 16) & 1u);
    return (unsigned short)(u >> 16);
}
// pack two fp32 -> two truncated bf16 in ONE v_perm_b32
__device__ inline unsigned permpack(float a, float b) {
    return __builtin_amdgcn_perm(__builtin_bit_cast(unsigned, b),
                                 __builtin_bit_cast(unsigned, a), 0x07060302u);
}
// select low shorts / high shorts of two packed-bf16 words (for bf16 transpose)
__device__ inline unsigned permlo(unsigned lo, unsigned hi) {
    return __builtin_amdgcn_perm(hi, lo, 0x05040100u);
}
__device__ inline unsigned permhi(unsigned lo, unsigned hi) {
    return __builtin_amdgcn_perm(hi, lo, 0x07060302u);
}
// async 16B global -> LDS (linear dest: wave-uniform base + lane*16)
__device__ inline void gload_lds16(const short* g, short* l) {
    __builtin_amdgcn_global_load_lds(
        (const __attribute__((address_space(1))) void*)(g),
        (__attribute__((address_space(3))) void*)(l), 16, 0, 0);
}

// ---- convert: x fp32 -> ybf bf16 (straight only; tiers 0b/1) ---------------
__global__ __launch_bounds__(256) void tobf16_kernel(const float* __restrict__ x,
                                                     short* __restrict__ ybf) {
    const size_t total = (size_t)8 * 512 * 9216 / 8;   // uint4 units (8 bf16)
    const size_t stride = (size_t)gridDim.x * 256;
    for (size_t i = (size_t)blockIdx.x * 256 + threadIdx.x; i < total; i += stride) {
        const float4 a = ((const float4*)x)[2 * i];
        const float4 b = ((const float4*)x)[2 * i + 1];
        uint4 pv;
        pv.x = permpack(a.x, a.y);
        pv.y = permpack(a.z, a.w);
        pv.z = permpack(b.x, b.y);
        pv.w = permpack(b.z, b.w);
        ((uint4*)ybf)[i] = pv;
    }
}

// ---- fused convert + transpose: x -> ybf [c][n] AND ytr [n][c] (tier-0) ----
// grid (N/64, C/64, B), 256 thr; thread owns a 4c x 4n block (ca=t&15, nb=t>>4).
__global__ __launch_bounds__(256) void convtr_kernel(const float* __restrict__ x,
                                                     short* __restrict__ ybf,
                                                     short* __restrict__ ytr) {
    const int C = 512, N = 9216;
    const int b = blockIdx.z, cB = blockIdx.y * 64, nB = blockIdx.x * 64;
    const int t = threadIdx.x, ca = t & 15, nb = t >> 4;
    const float* X = x + ((size_t)b * C + cB) * N + nB;
    float4 v[4];
    #pragma unroll
    for (int r = 0; r < 4; ++r)
        v[r] = *(const float4*)(X + (size_t)(ca * 4 + r) * N + nb * 4);
    // straight bf16 [c][n]
    short* Yb = ybf + ((size_t)b * C + cB) * N + nB;
    #pragma unroll
    for (int r = 0; r < 4; ++r) {
        uint2 p = make_uint2(permpack(v[r].x, v[r].y), permpack(v[r].z, v[r].w));
        *(uint2*)(Yb + (size_t)(ca * 4 + r) * N + nb * 4) = p;
    }
    // transposed bf16 [n][c]
    short* Yt = ytr + ((size_t)b * N + nB) * C + cB;
    {
        uint2 p0 = make_uint2(permpack(v[0].x, v[1].x), permpack(v[2].x, v[3].x));
        uint2 p1 = make_uint2(permpack(v[0].y, v[1].y), permpack(v[2].y, v[3].y));
        uint2 p2 = make_uint2(permpack(v[0].z, v[1].z), permpack(v[2].z, v[3].z));
        uint2 p3 = make_uint2(permpack(v[0].w, v[1].w), permpack(v[2].w, v[3].w));
        *(uint2*)(Yt + (size_t)(nb * 4 + 0) * C + ca * 4) = p0;
        *(uint2*)(Yt + (size_t)(nb * 4 + 1) * C + ca * 4) = p1;
        *(uint2*)(Yt + (size_t)(nb * 4 + 2) * C + ca * 4) = p2;
        *(uint2*)(Yt + (size_t)(nb * 4 + 3) * C + ca * 4) = p3;
    }
}

// ---- bf16 transpose: ybf [c][n] -> ytr [n][c] (tier-0b, after rsoftmax) ----
__global__ __launch_bounds__(256) void trbf_kernel(const short* __restrict__ ybf,
                                                   short* __restrict__ ytr) {
    const int C = 512, N = 9216;
    const int b = blockIdx.z, cB = blockIdx.y * 64, nB = blockIdx.x * 64;
    const int t = threadIdx.x, ca = t & 15, nb = t >> 4;
    const short* Yb = ybf + ((size_t)b * C + cB) * N + nB;
    uint2 rr[4];
    #pragma unroll
    for (int r = 0; r < 4; ++r)
        rr[r] = *(const uint2*)(Yb + (size_t)(ca * 4 + r) * N + nb * 4);
    short* Yt = ytr + ((size_t)b * N + nB) * C + cB;
    uint2 p0 = make_uint2(permlo(rr[0].x, rr[1].x), permlo(rr[2].x, rr[3].x));
    uint2 p1 = make_uint2(permhi(rr[0].x, rr[1].x), permhi(rr[2].x, rr[3].x));
    uint2 p2 = make_uint2(permlo(rr[0].y, rr[1].y), permlo(rr[2].y, rr[3].y));
    uint2 p3 = make_uint2(permhi(rr[0].y, rr[1].y), permhi(rr[2].y, rr[3].y));
    *(uint2*)(Yt + (size_t)(nb * 4 + 0) * C + ca * 4) = p0;
    *(uint2*)(Yt + (size_t)(nb * 4 + 1) * C + ca * 4) = p1;
    *(uint2*)(Yt + (size_t)(nb * 4 + 2) * C + ca * 4) = p2;
    *(uint2*)(Yt + (size_t)(nb * 4 + 3) * C + ca * 4) = p3;
}

// ---- GEMM1: partial[b][split] = Y Y^T slice, symmetric pairs, plain stores -
// 1D grid 640: xcd=id&7 -> batch; slot=id>>3 in [0,80): split=slot/10, pair=slot%10.
// LDS: packed [128][64] shorts, 16B unit u of row r holds global unit u^(r&7).
__global__ __launch_bounds__(256, 2) void gram_kernel4(const short* __restrict__ ybf,
                                                       float* __restrict__ part) {
    const int C = 512, N = 9216;
    __shared__ short As[2][GT * BK];
    __shared__ short Bs[2][GT * BK];
    const int id = blockIdx.x;
    const int batch = id & 7;
    const int slot = id >> 3;
    const int split = slot / 10;
    const int pair = slot % 10;
    const int i_ = (pair < 4) ? 0 : (pair < 7) ? 1 : (pair < 9) ? 2 : 3;
    const int j_ = pair - ((i_ == 0) ? 0 : (i_ == 1) ? 3 : (i_ == 2) ? 5 : 6);
    const bool diag = (i_ == j_);
    const int c0 = i_ * GT, d0 = j_ * GT;
    const short* Y = ybf + (size_t)batch * C * N;
    const int t = threadIdx.x;
    const int w = t >> 6, l = t & 63;
    const int mw = (w >> 1) * 64, nw = (w & 1) * 64;
    const int lr = l & 15, lq = l >> 4;

    const int kw = N / NSPLIT;                          // 1152 -> 18 iters
    const int kbeg = split * kw;
    const int nt = kw / BK;

    auto STAGE = [&](int ti, int buf) {
        const int k0 = kbeg + ti * BK;
        #pragma unroll
        for (int p = 0; p < 4; ++p) {                   // A: 1024 16B units
            const int u = t + p * 256;
            const int row = u >> 3;
            const int us = (u ^ row) & 7;
            gload_lds16(Y + (size_t)(c0 + row) * N + k0 + us * 8, &As[buf][u * 8]);
        }
        if (!diag) {
            #pragma unroll
            for (int p = 0; p < 4; ++p) {
                const int u = t + p * 256;
                const int row = u >> 3;
                const int us = (u ^ row) & 7;
                gload_lds16(Y + (size_t)(d0 + row) * N + k0 + us * 8, &Bs[buf][u * 8]);
            }
        }
    };

    f32x4 acc[4][4] = {};
    STAGE(0, 0);
    __syncthreads();
    int cur = 0;
    for (int ti = 0; ti < nt; ++ti) {
        if (ti + 1 < nt) STAGE(ti + 1, cur ^ 1);        // prefetch overlaps MFMA
        const short* Acur = &As[cur][0];
        const short* Bcur = diag ? &As[cur][0] : &Bs[cur][0];
        #pragma unroll
        for (int h = 0; h < 2; ++h) {
            short8 af[4], bf[4];
            #pragma unroll
            for (int i = 0; i < 4; i++) {
                const int r = mw + i * 16 + lr;
                af[i] = *(const short8*)&Acur[r * BK + (((h * 4 + lq) ^ (r & 7)) * 8)];
            }
            #pragma unroll
            for (int j = 0; j < 4; j++) {
                const int r = nw + j * 16 + lr;
                bf[j] = *(const short8*)&Bcur[r * BK + (((h * 4 + lq) ^ (r & 7)) * 8)];
            }
            #pragma unroll
            for (int i = 0; i < 4; i++)
                #pragma unroll
                for (int j = 0; j < 4; j++)
                    acc[i][j] = __builtin_amdgcn_mfma_f32_16x16x32_bf16(af[i], bf[j], acc[i][j], 0, 0, 0);
        }
        __syncthreads();
        cur ^= 1;
    }
    // C/D layout: col = lane&15, row = (lane>>4)*4 + r. Plain stores.
    float* P = part + ((size_t)batch * NSPLIT + split) * C * C;
    #pragma unroll
    for (int i = 0; i < 4; i++)
        #pragma unroll
        for (int j = 0; j < 4; j++)
            #pragma unroll
            for (int r = 0; r < 4; r++) {
                const int row = c0 + mw + i * 16 + lq * 4 + r;
                const int col = d0 + nw + j * 16 + lr;
                const float v = acc[i][j][r];
                P[(size_t)row * C + col] = v;
                if (!diag) P[(size_t)col * C + row] = v;
            }
}

// ---- fused split-reduce + softmax; emits compact bf16 att [C][C] -----------
__global__ __launch_bounds__(256) void rsoftmax_kernel(const float* __restrict__ part,
                                                       unsigned short* __restrict__ attbf) {
    const int C = 512;
    const int b = blockIdx.x >> 9;            // blockIdx.x in [0, B*C)
    const int row = blockIdx.x & 511;
    const float* P0 = part + (size_t)b * NSPLIT * C * C + (size_t)row * C;
    const int t = threadIdx.x;
    float v0 = 0.f, v1 = 0.f;
    #pragma unroll
    for (int s = 0; s < NSPLIT; ++s) {
        const float* Ps = P0 + (size_t)s * C * C;
        v0 += Ps[t];
        v1 += Ps[t + 256];
    }

    float mn = fminf(v0, v1);
    #pragma unroll
    for (int off = 32; off > 0; off >>= 1) mn = fminf(mn, __shfl_xor(mn, off));
    __shared__ float redmin[4];
    const int wid = t >> 6, lane = t & 63;
    if (lane == 0) redmin[wid] = mn;
    __syncthreads();
    mn = fminf(fminf(redmin[0], redmin[1]), fminf(redmin[2], redmin[3]));

    const float e0 = expf(mn - v0), e1 = expf(mn - v1);
    float s = e0 + e1;
    #pragma unroll
    for (int off = 32; off > 0; off >>= 1) s += __shfl_xor(s, off);
    __shared__ float redsum[4];
    if (lane == 0) redsum[wid] = s;
    __syncthreads();
    s = redsum[0] + redsum[1] + redsum[2] + redsum[3];

    const float inv = 1.0f / s;
    unsigned short* A16 = attbf + (size_t)b * C * C + (size_t)row * C;
    A16[t] = f2bf(e0 * inv);
    A16[t + 256] = f2bf(e1 * inv);
}

// ---- GEMM2: out = gamma*(A Y) + x; BOTH tiles via DMA (conflict-free) ------
// A from compact attbf [c][d]; B from ytr [n][d]. 1D grid 2304, batch-pinned,
// n-major within batch. Same staging/read structure as gram (0 conflicts).
__global__ __launch_bounds__(256, 2) void feat_kernel5(const short* __restrict__ attbf,
                                                       const short* __restrict__ ytr,
                                                       const float* __restrict__ x,
                                                       const float* __restrict__ gamma,
                                                       float* __restrict__ out) {
    const int C = 512, N = 9216;
    __shared__ short As[2][GT * BK];
    __shared__ short Bs[2][GT * BK];
    const int id = blockIdx.x;
    const int b = id & 7;
    const int slot = id >> 3;
    const int n0 = (slot >> 2) * GT;
    const int c0 = (slot & 3) * GT;
    const short* Ab = attbf + (size_t)b * C * C;        // [c][d], stride C
    const short* Yt = ytr + (size_t)b * N * C;          // [n][d], stride C
    const int t = threadIdx.x;
    const int w = t >> 6, l = t & 63;
    const int mw = (w >> 1) * 64, nw = (w & 1) * 64;
    const int lr = l & 15, lq = l >> 4;

    const int nt = C / BK;                // 8

    auto STAGE = [&](int ti, int buf) {
        const int k0 = ti * BK;
        #pragma unroll
        for (int p = 0; p < 4; ++p) {                   // A tile
            const int u = t + p * 256;
            const int row = u >> 3;
            const int us = (u ^ row) & 7;
            gload_lds16(Ab + (size_t)(c0 + row) * C + k0 + us * 8, &As[buf][u * 8]);
        }
        #pragma unroll
        for (int p = 0; p < 4; ++p) {                   // B tile (Y^T rows)
            const int u = t + p * 256;
            const int row = u >> 3;
            const int us = (u ^ row) & 7;
            gload_lds16(Yt + (size_t)(n0 + row) * C + k0 + us * 8, &Bs[buf][u * 8]);
        }
    };

    f32x4 acc[4][4] = {};
    STAGE(0, 0);
    __syncthreads();
    int cur = 0;
    for (int ti = 0; ti < nt; ++ti) {
        if (ti + 1 < nt) STAGE(ti + 1, cur ^ 1);        // prefetch overlaps MFMA
        #pragma unroll
        for (int h = 0; h < 2; ++h) {
            short8 af[4], bf[4];
            #pragma unroll
            for (int i = 0; i < 4; i++) {
                const int r = mw + i * 16 + lr;
                af[i] = *(const short8*)&As[cur][r * BK + (((h * 4 + lq) ^ (r & 7)) * 8)];
            }
            #pragma unroll
            for (int j = 0; j < 4; j++) {
                const int r = nw + j * 16 + lr;
                bf[j] = *(const short8*)&Bs[cur][r * BK + (((h * 4 + lq) ^ (r & 7)) * 8)];
            }
            #pragma unroll
            for (int i = 0; i < 4; i++)
                #pragma unroll
                for (int j = 0; j < 4; j++)
                    acc[i][j] = __builtin_amdgcn_mfma_f32_16x16x32_bf16(af[i], bf[j], acc[i][j], 0, 0, 0);
        }
        __syncthreads();
        cur ^= 1;
    }

    const float g = gamma[0];
    float* O = out + (size_t)b * C * N;
    const float* X = x + (size_t)b * C * N;
    #pragma unroll
    for (int i = 0; i < 4; i++)
        #pragma unroll
        for (int j = 0; j < 4; j++)
            #pragma unroll
            for (int r = 0; r < 4; r++) {
                const int row = c0 + mw + i * 16 + lq * 4 + r;
                const int col = n0 + nw + j * 16 + lr;
                const size_t idx = (size_t)row * N + col;
                O[idx] = g * acc[i][j][r] + X[idx];
            }
}

// ---- tier-1 feat (v4, register B-transpose; verified at 427us total) -------
__global__ __launch_bounds__(256, 2) void feat_kernel4(const short* __restrict__ attbf,
                                                       const short* __restrict__ ybf,
                                                       const float* __restrict__ x,
                                                       const float* __restrict__ gamma,
                                                       float* __restrict__ out) {
    const int C = 512, N = 9216;
    __shared__ short As[2][GT * BK];
    __shared__ short Bs[2][GT * BK];
    const int id = blockIdx.x;
    const int b = id & 7;
    const int slot = id >> 3;
    const int n0 = (slot >> 2) * GT;
    const int c0 = (slot & 3) * GT;
    const short* Ab = attbf + (size_t)b * C * C;
    const short* Y = ybf + (size_t)b * C * N;
    const int t = threadIdx.x;
    const int w = t >> 6, l = t & 63;
    const int mw = (w >> 1) * 64, nw = (w & 1) * 64;
    const int lr = l & 15, lq = l >> 4;
    const int ng = t & 31, kg = t >> 5;

    const int nt = C / BK;

    auto ASTAGE = [&](int ti, int buf) {
        const int k0 = ti * BK;
        #pragma unroll
        for (int p = 0; p < 4; ++p) {
            const int u = t + p * 256;
            const int row = u >> 3;
            const int us = (u ^ row) & 7;
            gload_lds16(Ab + (size_t)(c0 + row) * C + k0 + us * 8, &As[buf][u * 8]);
        }
    };

    uint2 rr[8];
    auto BLOAD = [&](int ti) {
        const short* pB = Y + (size_t)(ti * BK + kg * 8) * N + n0 + ng * 4;
        #pragma unroll
        for (int r = 0; r < 8; ++r) rr[r] = *(const uint2*)(pB + (size_t)r * N);
    };
    auto BWRITE = [&](int buf) {
        #pragma unroll
        for (int j = 0; j < 4; ++j) {
            const unsigned sel = (j & 1) ? 0x07060302u : 0x05040100u;
            unsigned w0, w1, w2, w3;
            if (j < 2) {
                w0 = __builtin_amdgcn_perm(rr[1].x, rr[0].x, sel);
                w1 = __builtin_amdgcn_perm(rr[3].x, rr[2].x, sel);
                w2 = __builtin_amdgcn_perm(rr[5].x, rr[4].x, sel);
                w3 = __builtin_amdgcn_perm(rr[7].x, rr[6].x, sel);
            } else {
                w0 = __builtin_amdgcn_perm(rr[1].y, rr[0].y, sel);
                w1 = __builtin_amdgcn_perm(rr[3].y, rr[2].y, sel);
                w2 = __builtin_amdgcn_perm(rr[5].y, rr[4].y, sel);
                w3 = __builtin_amdgcn_perm(rr[7].y, rr[6].y, sel);
            }
            const int nrow = ng * 4 + j;
            uint4 cv; cv.x = w0; cv.y = w1; cv.z = w2; cv.w = w3;
            *(uint4*)&Bs[buf][nrow * BK + ((kg ^ (nrow & 7)) * 8)] = cv;
        }
    };

    f32x4 acc[4][4] = {};
    BLOAD(0);
    ASTAGE(0, 0);
    BWRITE(0);
    __syncthreads();
    int cur = 0;
    for (int ti = 0; ti < nt; ++ti) {
        if (ti + 1 < nt) {
            BLOAD(ti + 1);
            ASTAGE(ti + 1, cur ^ 1);
        }
        #pragma unroll
        for (int h = 0; h < 2; ++h) {
            short8 af[4], bf[4];
            #pragma unroll
            for (int i = 0; i < 4; i++) {
                const int r = mw + i * 16 + lr;
                af[i] = *(const short8*)&As[cur][r * BK + (((h * 4 + lq) ^ (r & 7)) * 8)];
            }
            #pragma unroll
            for (int j = 0; j < 4; j++) {
                const int r = nw + j * 16 + lr;
                bf[j] = *(const short8*)&Bs[cur][r * BK + (((h * 4 + lq) ^ (r & 7)) * 8)];
            }
            #pragma unroll
            for (int i = 0; i < 4; i++)
                #pragma unroll
                for (int j = 0; j < 4; j++)
                    acc[i][j] = __builtin_amdgcn_mfma_f32_16x16x32_bf16(af[i], bf[j], acc[i][j], 0, 0, 0);
        }
        if (ti + 1 < nt) BWRITE(cur ^ 1);
        __syncthreads();
        cur ^= 1;
    }

    const float g = gamma[0];
    float* O = out + (size_t)b * C * N;
    const float* X = x + (size_t)b * C * N;
    #pragma unroll
    for (int i = 0; i < 4; i++)
        #pragma unroll
        for (int j = 0; j < 4; j++)
            #pragma unroll
            for (int r = 0; r < 4; r++) {
                const int row = c0 + mw + i * 16 + lq * 4 + r;
                const int col = n0 + nw + j * 16 + lr;
                const size_t idx = (size_t)row * N + col;
                O[idx] = g * acc[i][j][r] + X[idx];
            }
}

// ======================= tier-3 path (fp32-staged, verified) ================
__global__ __launch_bounds__(256, 2) void gram_fb(const float* __restrict__ x,
                                                  float* __restrict__ att,
                                                  int C, int N) {
    __shared__ short As[GT * LDA];
    __shared__ short Bs[GT * LDA];
    const int bz = blockIdx.z;
    const int batch = bz & 7, split = bz >> 3;
    const int c0 = blockIdx.y * GT;
    const int d0 = blockIdx.x * GT;
    const float* Y = x + (size_t)batch * C * N;
    const int t = threadIdx.x;
    const int w = t >> 6, l = t & 63;
    const int mw = (w >> 1) * 64, nw = (w & 1) * 64;
    const int lr = l & 15, lq = l >> 4;

    f32x4 acc[4][4] = {};
    const int kbeg = split * (N / FBSPLIT);
    const int kend = kbeg + (N / FBSPLIT);
    for (int k0 = kbeg; k0 < kend; k0 += BK) {
        #pragma unroll
        for (int i = 0; i < 8; i++) {
            const int v = t + i * 256;
            const int row = v >> 4, kq = v & 15;
            float4 a = *(const float4*)(Y + (size_t)(c0 + row) * N + k0 + kq * 4);
            uint2 pa = make_uint2(permpack(a.x, a.y), permpack(a.z, a.w));
            *(uint2*)&As[row * LDA + kq * 4] = pa;
            float4 bv = *(const float4*)(Y + (size_t)(d0 + row) * N + k0 + kq * 4);
            uint2 pb = make_uint2(permpack(bv.x, bv.y), permpack(bv.z, bv.w));
            *(uint2*)&Bs[row * LDA + kq * 4] = pb;
        }
        __syncthreads();
        #pragma unroll
        for (int h = 0; h < 2; h++) {
            short8 af[4], bf[4];
            #pragma unroll
            for (int i = 0; i < 4; i++)
                af[i] = *(short8*)&As[(mw + i * 16 + lr) * LDA + h * 32 + lq * 8];
            #pragma unroll
            for (int j = 0; j < 4; j++)
                bf[j] = *(short8*)&Bs[(nw + j * 16 + lr) * LDA + h * 32 + lq * 8];
            #pragma unroll
            for (int i = 0; i < 4; i++)
                #pragma unroll
                for (int j = 0; j < 4; j++)
                    acc[i][j] = __builtin_amdgcn_mfma_f32_16x16x32_bf16(af[i], bf[j], acc[i][j], 0, 0, 0);
        }
        __syncthreads();
    }
    float* S = att + (size_t)batch * C * C;
    #pragma unroll
    for (int i = 0; i < 4; i++)
        #pragma unroll
        for (int j = 0; j < 4; j++)
            #pragma unroll
            for (int r = 0; r < 4; r++) {
                const int row = c0 + mw + i * 16 + lq * 4 + r;
                const int col = d0 + nw + j * 16 + lr;
                unsafeAtomicAdd(&S[(size_t)row * C + col], acc[i][j][r]);
            }
}

__global__ __launch_bounds__(256) void softmax_kernel(float* __restrict__ att) {
    const int C = 512;
    float* S = att + (size_t)blockIdx.x * C;
    const int t = threadIdx.x;
    const float v0 = S[t], v1 = S[t + 256];

    float mn = fminf(v0, v1);
    #pragma unroll
    for (int off = 32; off > 0; off >>= 1) mn = fminf(mn, __shfl_xor(mn, off));
    __shared__ float redmin[4];
    const int wid = t >> 6, lane = t & 63;
    if (lane == 0) redmin[wid] = mn;
    __syncthreads();
    mn = fminf(fminf(redmin[0], redmin[1]), fminf(redmin[2], redmin[3]));

    const float e0 = expf(mn - v0), e1 = expf(mn - v1);
    float s = e0 + e1;
    #pragma unroll
    for (int off = 32; off > 0; off >>= 1) s += __shfl_xor(s, off);
    __shared__ float redsum[4];
    if (lane == 0) redsum[wid] = s;
    __syncthreads();
    s = redsum[0] + redsum[1] + redsum[2] + redsum[3];

    const float inv = 1.0f / s;
    unsigned short* S16 = (unsigned short*)S;
    S16[t] = f2bf(e0 * inv);
    S16[t + 256] = f2bf(e1 * inv);
}

__global__ __launch_bounds__(256, 2) void feat_fb(const float* __restrict__ att,
                                                  const float* __restrict__ x,
                                                  const float* __restrict__ gamma,
                                                  float* __restrict__ out,
                                                  int C, int N) {
    __shared__ short As[GT * LDA];
    __shared__ short Bs[GT * LDA];
    const int b  = blockIdx.z;
    const int c0 = blockIdx.y * GT;
    const int n0 = blockIdx.x * GT;
    const short* Ab = (const short*)(att + (size_t)b * C * C);
    const float* Y = x + (size_t)b * C * N;
    const int t = threadIdx.x;
    const int w = t >> 6, l = t & 63;
    const int mw = (w >> 1) * 64, nw = (w & 1) * 64;
    const int lr = l & 15, lq = l >> 4;

    f32x4 acc[4][4] = {};
    for (int k0 = 0; k0 < C; k0 += BK) {
        #pragma unroll
        for (int i = 0; i < 4; i++) {
            const int v = t + i * 256;
            const int row = v >> 3, q = v & 7;
            uint4 va = *(const uint4*)(Ab + (size_t)(c0 + row) * 1024 + k0 + q * 8);
            *(uint4*)&As[row * LDA + q * 8] = va;
        }
        #pragma unroll
        for (int i = 0; i < 2; i++) {
            const int v = t + i * 256;
            const int kg = v & 15, ng = v >> 4;
            const float* p0 = Y + (size_t)(k0 + kg * 4) * N + n0 + ng * 4;
            float4 r0 = *(const float4*)(p0);
            float4 r1 = *(const float4*)(p0 + N);
            float4 r2 = *(const float4*)(p0 + 2 * (size_t)N);
            float4 r3 = *(const float4*)(p0 + 3 * (size_t)N);
            const float j0[4] = {r0.x, r1.x, r2.x, r3.x};
            const float j1[4] = {r0.y, r1.y, r2.y, r3.y};
            const float j2[4] = {r0.z, r1.z, r2.z, r3.z};
            const float j3[4] = {r0.w, r1.w, r2.w, r3.w};
            const float* cols[4] = {j0, j1, j2, j3};
            #pragma unroll
            for (int j = 0; j < 4; j++) {
                uint2 p = make_uint2(permpack(cols[j][0], cols[j][1]),
                                     permpack(cols[j][2], cols[j][3]));
                *(uint2*)&Bs[(ng * 4 + j) * LDA + kg * 4] = p;
            }
        }
        __syncthreads();
        #pragma unroll
        for (int h = 0; h < 2; h++) {
            short8 af[4], bf[4];
            #pragma unroll
            for (int i = 0; i < 4; i++)
                af[i] = *(short8*)&As[(mw + i * 16 + lr) * LDA + h * 32 + lq * 8];
            #pragma unroll
            for (int j = 0; j < 4; j++)
                bf[j] = *(short8*)&Bs[(nw + j * 16 + lr) * LDA + h * 32 + lq * 8];
            #pragma unroll
            for (int i = 0; i < 4; i++)
                #pragma unroll
                for (int j = 0; j < 4; j++)
                    acc[i][j] = __builtin_amdgcn_mfma_f32_16x16x32_bf16(af[i], bf[j], acc[i][j], 0, 0, 0);
        }
        __syncthreads();
    }

    const float g = gamma[0];
    float* O = out + (size_t)b * C * N;
    const float* X = x + (size_t)b * C * N;
    #pragma unroll
    for (int i = 0; i < 4; i++)
        #pragma unroll
        for (int j = 0; j < 4; j++)
            #pragma unroll
            for (int r = 0; r < 4; r++) {
                const int row = c0 + mw + i * 16 + lq * 4 + r;
                const int col = n0 + nw + j * 16 + lr;
                const size_t idx = (size_t)row * N + col;
                O[idx] = g * acc[i][j][r] + X[idx];
            }
}

extern "C" void kernel_launch(void* const* d_in, const int* in_sizes, int n_in,
                              void* d_out, int out_size, void* d_ws, size_t ws_size,
                              hipStream_t stream) {
    const int B = 8, C = 512, N = 96 * 96;
    const float* x     = (const float*)d_in[0];
    const float* gamma = (const float*)d_in[1];
    float* out = (float*)d_out;
    const size_t attBytes  = (size_t)B * C * C * sizeof(float);           // 8 MB slot
    const size_t ybfBytes  = (size_t)B * C * N * sizeof(short);           // 72 MB
    const size_t ytrBytes  = (size_t)B * N * C * sizeof(short);           // 72 MB
    const size_t partBytes = (size_t)B * NSPLIT * C * C * sizeof(float);  // 64 MB

    dim3 blk(256);
    if (ws_size >= attBytes + ybfBytes + ytrBytes + partBytes) {
        // tier-0 (216 MB): fused conv+transpose; feat B via DMA from Y^T
        unsigned short* attbf = (unsigned short*)d_ws;
        short* ybf  = (short*)((char*)d_ws + attBytes);
        short* ytr  = (short*)((char*)d_ws + attBytes + ybfBytes);
        float* part = (float*)((char*)d_ws + attBytes + ybfBytes + ytrBytes);
        convtr_kernel<<<dim3(N / 64, C / 64, B), blk, 0, stream>>>(x, ybf, ytr);
        gram_kernel4<<<dim3(8 * NSPLIT * 10), blk, 0, stream>>>(ybf, part);
        rsoftmax_kernel<<<dim3(B * C), blk, 0, stream>>>(part, attbf);
        feat_kernel5<<<dim3(8 * 288), blk, 0, stream>>>((const short*)attbf, ytr, x, gamma, out);
    } else if (ws_size >= attBytes + ybfBytes + ytrBytes) {
        // tier-0b (152 MB): ytr overlays part (part dead after rsoftmax)
        unsigned short* attbf = (unsigned short*)d_ws;
        short* ybf  = (short*)((char*)d_ws + attBytes);
        char* region = (char*)d_ws + attBytes + ybfBytes;   // 72 MB >= part 64 MB
        float* part = (float*)region;
        short* ytr  = (short*)region;
        tobf16_kernel<<<2048, blk, 0, stream>>>(x, ybf);
        gram_kernel4<<<dim3(8 * NSPLIT * 10), blk, 0, stream>>>(ybf, part);
        rsoftmax_kernel<<<dim3(B * C), blk, 0, stream>>>(part, attbf);
        trbf_kernel<<<dim3(N / 64, C / 64, B), blk, 0, stream>>>(ybf, ytr);
        feat_kernel5<<<dim3(8 * 288), blk, 0, stream>>>((const short*)attbf, ytr, x, gamma, out);
    } else if (ws_size >= attBytes + ybfBytes + partBytes) {
        // tier-1 (144 MB): verified v4 path
        unsigned short* attbf = (unsigned short*)d_ws;
        short* ybf  = (short*)((char*)d_ws + attBytes);
        float* part = (float*)((char*)d_ws + attBytes + ybfBytes);
        tobf16_kernel<<<2048, blk, 0, stream>>>(x, ybf);
        gram_kernel4<<<dim3(8 * NSPLIT * 10), blk, 0, stream>>>(ybf, part);
        rsoftmax_kernel<<<dim3(B * C), blk, 0, stream>>>(part, attbf);
        feat_kernel4<<<dim3(8 * 288), blk, 0, stream>>>((const short*)attbf, ybf, x, gamma, out);
    } else {
        // tier-3: fp32-staged verified path (8 MB)
        float* att = (float*)d_ws;
        hipMemsetAsync(att, 0, attBytes, stream);
        gram_fb<<<dim3(C / GT, C / GT, B * FBSPLIT), blk, 0, stream>>>(x, att, C, N);
        softmax_kernel<<<dim3(B * C), blk, 0, stream>>>(att);
        feat_fb<<<dim3(N / GT, C / GT, B), blk, 0, stream>>>(att, x, gamma, out, C, N);
    }
}

// Round 6
// 425.705 us; speedup vs baseline: 1.0634x; 1.0634x over previous
//
#include <hip/hip_runtime.h>

// ChannelAttentionModule (DANet channel attention) via bf16 MFMA.
// x: [B=8, C=512, N=96*96=9216] fp32, gamma scalar.
// v6: drop ytr/trbf/convtr entirely. feat reads ybf with the v4 register 4x4
// B-transpose, but (a) B-LDS row stride padded to 36 shorts (72B) -> write
// conflicts 16-way -> ~2-way (free), reads via b64 pairs conflict-free;
// (b) BK=32 halves LDS to 34KB -> launch_bounds(256,3), 3 blocks/CU.
// Pipeline: tobf16 -> gram4 (verified) -> rsoftmax -> feat6. 144 MB workspace.

typedef __attribute__((ext_vector_type(8))) short short8;    // 8 bf16 = 4 VGPR
typedef __attribute__((ext_vector_type(4))) short short4v;   // 4 bf16 = 2 VGPR
typedef __attribute__((ext_vector_type(4))) float f32x4;     // MFMA C/D

#define GT 128      // gram/feat tile (M=N=128)
#define BK 64       // gram K-chunk (shorts)
#define BKF 32      // feat K-chunk (shorts)
#define PADB 36     // feat B-LDS row stride in shorts (72 B: 18-bank row rotate)
#define LDA 72      // fp32-fallback LDS row stride (shorts)
#define NSPLIT 8    // gram split-K
#define FBSPLIT 4   // fallback gram split-K

__device__ inline unsigned short f2bf(float f) {            // RNE (softmax only)
    unsigned u = __builtin_bit_cast(unsigned, f);
    u += 0x7fffu + ((u >> 16) & 1u);
    return (unsigned short)(u >> 16);
}
// pack two fp32 -> two truncated bf16 in ONE v_perm_b32
__device__ inline unsigned permpack(float a, float b) {
    return __builtin_amdgcn_perm(__builtin_bit_cast(unsigned, b),
                                 __builtin_bit_cast(unsigned, a), 0x07060302u);
}
// select low shorts / high shorts of two packed-bf16 words (HW-verified in r5)
__device__ inline unsigned permlo(unsigned lo, unsigned hi) {
    return __builtin_amdgcn_perm(hi, lo, 0x05040100u);
}
__device__ inline unsigned permhi(unsigned lo, unsigned hi) {
    return __builtin_amdgcn_perm(hi, lo, 0x07060302u);
}
// async 16B global -> LDS (linear dest: wave-uniform base + lane*16)
__device__ inline void gload_lds16(const short* g, short* l) {
    __builtin_amdgcn_global_load_lds(
        (const __attribute__((address_space(1))) void*)(g),
        (__attribute__((address_space(3))) void*)(l), 16, 0, 0);
}

// ---- convert: x fp32 -> ybf bf16 (truncate, matches MFMA input rounding) ----
__global__ __launch_bounds__(256) void tobf16_kernel(const float* __restrict__ x,
                                                     short* __restrict__ ybf) {
    const size_t total = (size_t)8 * 512 * 9216 / 8;   // uint4 units (8 bf16)
    const size_t stride = (size_t)gridDim.x * 256;
    for (size_t i = (size_t)blockIdx.x * 256 + threadIdx.x; i < total; i += stride) {
        const float4 a = ((const float4*)x)[2 * i];
        const float4 b = ((const float4*)x)[2 * i + 1];
        uint4 pv;
        pv.x = permpack(a.x, a.y);
        pv.y = permpack(a.z, a.w);
        pv.z = permpack(b.x, b.y);
        pv.w = permpack(b.z, b.w);
        ((uint4*)ybf)[i] = pv;
    }
}

// ---- GEMM1: partial[b][split] = Y Y^T slice, symmetric pairs, plain stores -
// 1D grid 640: xcd=id&7 -> batch; slot=id>>3 in [0,80): split=slot/10, pair=slot%10.
// LDS: packed [128][64] shorts, 16B unit u of row r holds global unit u^(r&7).
__global__ __launch_bounds__(256, 2) void gram_kernel4(const short* __restrict__ ybf,
                                                       float* __restrict__ part) {
    const int C = 512, N = 9216;
    __shared__ short As[2][GT * BK];
    __shared__ short Bs[2][GT * BK];
    const int id = blockIdx.x;
    const int batch = id & 7;
    const int slot = id >> 3;
    const int split = slot / 10;
    const int pair = slot % 10;
    const int i_ = (pair < 4) ? 0 : (pair < 7) ? 1 : (pair < 9) ? 2 : 3;
    const int j_ = pair - ((i_ == 0) ? 0 : (i_ == 1) ? 3 : (i_ == 2) ? 5 : 6);
    const bool diag = (i_ == j_);
    const int c0 = i_ * GT, d0 = j_ * GT;
    const short* Y = ybf + (size_t)batch * C * N;
    const int t = threadIdx.x;
    const int w = t >> 6, l = t & 63;
    const int mw = (w >> 1) * 64, nw = (w & 1) * 64;
    const int lr = l & 15, lq = l >> 4;

    const int kw = N / NSPLIT;                          // 1152 -> 18 iters
    const int kbeg = split * kw;
    const int nt = kw / BK;

    auto STAGE = [&](int ti, int buf) {
        const int k0 = kbeg + ti * BK;
        #pragma unroll
        for (int p = 0; p < 4; ++p) {                   // A: 1024 16B units
            const int u = t + p * 256;
            const int row = u >> 3;
            const int us = (u ^ row) & 7;
            gload_lds16(Y + (size_t)(c0 + row) * N + k0 + us * 8, &As[buf][u * 8]);
        }
        if (!diag) {
            #pragma unroll
            for (int p = 0; p < 4; ++p) {
                const int u = t + p * 256;
                const int row = u >> 3;
                const int us = (u ^ row) & 7;
                gload_lds16(Y + (size_t)(d0 + row) * N + k0 + us * 8, &Bs[buf][u * 8]);
            }
        }
    };

    f32x4 acc[4][4] = {};
    STAGE(0, 0);
    __syncthreads();
    int cur = 0;
    for (int ti = 0; ti < nt; ++ti) {
        if (ti + 1 < nt) STAGE(ti + 1, cur ^ 1);        // prefetch overlaps MFMA
        const short* Acur = &As[cur][0];
        const short* Bcur = diag ? &As[cur][0] : &Bs[cur][0];
        #pragma unroll
        for (int h = 0; h < 2; ++h) {
            short8 af[4], bf[4];
            #pragma unroll
            for (int i = 0; i < 4; i++) {
                const int r = mw + i * 16 + lr;
                af[i] = *(const short8*)&Acur[r * BK + (((h * 4 + lq) ^ (r & 7)) * 8)];
            }
            #pragma unroll
            for (int j = 0; j < 4; j++) {
                const int r = nw + j * 16 + lr;
                bf[j] = *(const short8*)&Bcur[r * BK + (((h * 4 + lq) ^ (r & 7)) * 8)];
            }
            #pragma unroll
            for (int i = 0; i < 4; i++)
                #pragma unroll
                for (int j = 0; j < 4; j++)
                    acc[i][j] = __builtin_amdgcn_mfma_f32_16x16x32_bf16(af[i], bf[j], acc[i][j], 0, 0, 0);
        }
        __syncthreads();
        cur ^= 1;
    }
    // C/D layout: col = lane&15, row = (lane>>4)*4 + r. Plain stores.
    float* P = part + ((size_t)batch * NSPLIT + split) * C * C;
    #pragma unroll
    for (int i = 0; i < 4; i++)
        #pragma unroll
        for (int j = 0; j < 4; j++)
            #pragma unroll
            for (int r = 0; r < 4; r++) {
                const int row = c0 + mw + i * 16 + lq * 4 + r;
                const int col = d0 + nw + j * 16 + lr;
                const float v = acc[i][j][r];
                P[(size_t)row * C + col] = v;
                if (!diag) P[(size_t)col * C + row] = v;
            }
}

// ---- fused split-reduce + softmax; emits compact bf16 att [C][C] -----------
__global__ __launch_bounds__(256) void rsoftmax_kernel(const float* __restrict__ part,
                                                       unsigned short* __restrict__ attbf) {
    const int C = 512;
    const int b = blockIdx.x >> 9;            // blockIdx.x in [0, B*C)
    const int row = blockIdx.x & 511;
    const float* P0 = part + (size_t)b * NSPLIT * C * C + (size_t)row * C;
    const int t = threadIdx.x;
    float v0 = 0.f, v1 = 0.f;
    #pragma unroll
    for (int s = 0; s < NSPLIT; ++s) {
        const float* Ps = P0 + (size_t)s * C * C;
        v0 += Ps[t];
        v1 += Ps[t + 256];
    }

    float mn = fminf(v0, v1);
    #pragma unroll
    for (int off = 32; off > 0; off >>= 1) mn = fminf(mn, __shfl_xor(mn, off));
    __shared__ float redmin[4];
    const int wid = t >> 6, lane = t & 63;
    if (lane == 0) redmin[wid] = mn;
    __syncthreads();
    mn = fminf(fminf(redmin[0], redmin[1]), fminf(redmin[2], redmin[3]));

    const float e0 = expf(mn - v0), e1 = expf(mn - v1);
    float s = e0 + e1;
    #pragma unroll
    for (int off = 32; off > 0; off >>= 1) s += __shfl_xor(s, off);
    __shared__ float redsum[4];
    if (lane == 0) redsum[wid] = s;
    __syncthreads();
    s = redsum[0] + redsum[1] + redsum[2] + redsum[3];

    const float inv = 1.0f / s;
    unsigned short* A16 = attbf + (size_t)b * C * C + (size_t)row * C;
    A16[t] = f2bf(e0 * inv);
    A16[t + 256] = f2bf(e1 * inv);
}

// ---- GEMM2: out = gamma*(A Y) + x; BK=32, padded-B reg-transpose -----------
// A: compact attbf via swizzled DMA ([128][32], unit-XOR row&3).
// B: ybf 4x4 reg transpose -> [128][PADB=36] (72B rows: writes ~2-way, b64
// reads conflict-free). 1D grid 2304, batch-pinned XCD, n-major per batch.
__global__ __launch_bounds__(256, 3) void feat_kernel6(const short* __restrict__ attbf,
                                                       const short* __restrict__ ybf,
                                                       const float* __restrict__ x,
                                                       const float* __restrict__ gamma,
                                                       float* __restrict__ out) {
    const int C = 512, N = 9216;
    __shared__ short As[2][GT * BKF];     // 2 x 8 KB
    __shared__ short Bs[2][GT * PADB];    // 2 x 9 KB
    const int id = blockIdx.x;
    const int b = id & 7;
    const int slot = id >> 3;
    const int n0 = (slot >> 2) * GT;
    const int c0 = (slot & 3) * GT;
    const short* Ab = attbf + (size_t)b * C * C;        // [c][d], stride C
    const short* Y = ybf + (size_t)b * C * N;           // [d][n], stride N
    const int t = threadIdx.x;
    const int w = t >> 6, l = t & 63;
    const int mw = (w >> 1) * 64, nw = (w & 1) * 64;
    const int lr = l & 15, lq = l >> 4;
    const int ng = t & 31, kd = t >> 5;   // B micro-tile: 4 d-rows x 4 n-cols

    const int nt = C / BKF;               // 16

    auto ASTAGE = [&](int ti, int buf) {
        const int k0 = ti * BKF;
        #pragma unroll
        for (int p = 0; p < 2; ++p) {                   // 512 16B units
            const int u = t + p * 256;
            const int row = u >> 2;
            const int us = (u ^ row) & 3;
            gload_lds16(Ab + (size_t)(c0 + row) * C + k0 + us * 8, &As[buf][u * 8]);
        }
    };

    uint2 rr[4];
    auto BLOAD = [&](int ti) {
        const short* pB = Y + (size_t)(ti * BKF + kd * 4) * N + n0 + ng * 4;
        #pragma unroll
        for (int r = 0; r < 4; ++r) rr[r] = *(const uint2*)(pB + (size_t)r * N);
    };
    auto BWRITE = [&](int buf) {
        // 4x4 bf16 transpose (permlo/permhi HW-verified via r5's trbf)
        short* base = &Bs[buf][0];
        const int bo = kd * 4;
        *(uint2*)&base[(ng * 4 + 0) * PADB + bo] =
            make_uint2(permlo(rr[0].x, rr[1].x), permlo(rr[2].x, rr[3].x));
        *(uint2*)&base[(ng * 4 + 1) * PADB + bo] =
            make_uint2(permhi(rr[0].x, rr[1].x), permhi(rr[2].x, rr[3].x));
        *(uint2*)&base[(ng * 4 + 2) * PADB + bo] =
            make_uint2(permlo(rr[0].y, rr[1].y), permlo(rr[2].y, rr[3].y));
        *(uint2*)&base[(ng * 4 + 3) * PADB + bo] =
            make_uint2(permhi(rr[0].y, rr[1].y), permhi(rr[2].y, rr[3].y));
    };

    f32x4 acc[4][4] = {};
    BLOAD(0);
    ASTAGE(0, 0);
    BWRITE(0);                       // waits only its own global loads
    __syncthreads();                 // drains A DMA + B ds_writes
    int cur = 0;
    for (int ti = 0; ti < nt; ++ti) {
        if (ti + 1 < nt) {
            BLOAD(ti + 1);           // issue-early: latency hides under MFMA
            ASTAGE(ti + 1, cur ^ 1);
        }
        {
            short8 af[4], bf[4];
            #pragma unroll
            for (int i = 0; i < 4; i++) {
                const int r = mw + i * 16 + lr;
                af[i] = *(const short8*)&As[cur][r * BKF + ((lq ^ (r & 3)) * 8)];
            }
            #pragma unroll
            for (int j = 0; j < 4; j++) {
                const int r = nw + j * 16 + lr;
                const short* p = &Bs[cur][r * PADB + lq * 8];
                short4v blo = *(const short4v*)p;         // b64, 8B-aligned
                short4v bhi = *(const short4v*)(p + 4);
                bf[j] = __builtin_shufflevector(blo, bhi, 0, 1, 2, 3, 4, 5, 6, 7);
            }
            #pragma unroll
            for (int i = 0; i < 4; i++)
                #pragma unroll
                for (int j = 0; j < 4; j++)
                    acc[i][j] = __builtin_amdgcn_mfma_f32_16x16x32_bf16(af[i], bf[j], acc[i][j], 0, 0, 0);
        }
        if (ti + 1 < nt) BWRITE(cur ^ 1);   // write-late: after MFMA phase
        __syncthreads();
        cur ^= 1;
    }

    const float g = gamma[0];
    float* O = out + (size_t)b * C * N;
    const float* X = x + (size_t)b * C * N;
    #pragma unroll
    for (int i = 0; i < 4; i++)
        #pragma unroll
        for (int j = 0; j < 4; j++)
            #pragma unroll
            for (int r = 0; r < 4; r++) {
                const int row = c0 + mw + i * 16 + lq * 4 + r;
                const int col = n0 + nw + j * 16 + lr;
                const size_t idx = (size_t)row * N + col;
                O[idx] = g * acc[i][j][r] + X[idx];
            }
}

// ======================= fallback path (fp32-staged, verified) ==============
__global__ __launch_bounds__(256, 2) void gram_fb(const float* __restrict__ x,
                                                  float* __restrict__ att,
                                                  int C, int N) {
    __shared__ short As[GT * LDA];
    __shared__ short Bs[GT * LDA];
    const int bz = blockIdx.z;
    const int batch = bz & 7, split = bz >> 3;
    const int c0 = blockIdx.y * GT;
    const int d0 = blockIdx.x * GT;
    const float* Y = x + (size_t)batch * C * N;
    const int t = threadIdx.x;
    const int w = t >> 6, l = t & 63;
    const int mw = (w >> 1) * 64, nw = (w & 1) * 64;
    const int lr = l & 15, lq = l >> 4;

    f32x4 acc[4][4] = {};
    const int kbeg = split * (N / FBSPLIT);
    const int kend = kbeg + (N / FBSPLIT);
    for (int k0 = kbeg; k0 < kend; k0 += BK) {
        #pragma unroll
        for (int i = 0; i < 8; i++) {
            const int v = t + i * 256;
            const int row = v >> 4, kq = v & 15;
            float4 a = *(const float4*)(Y + (size_t)(c0 + row) * N + k0 + kq * 4);
            uint2 pa = make_uint2(permpack(a.x, a.y), permpack(a.z, a.w));
            *(uint2*)&As[row * LDA + kq * 4] = pa;
            float4 bv = *(const float4*)(Y + (size_t)(d0 + row) * N + k0 + kq * 4);
            uint2 pb = make_uint2(permpack(bv.x, bv.y), permpack(bv.z, bv.w));
            *(uint2*)&Bs[row * LDA + kq * 4] = pb;
        }
        __syncthreads();
        #pragma unroll
        for (int h = 0; h < 2; h++) {
            short8 af[4], bf[4];
            #pragma unroll
            for (int i = 0; i < 4; i++)
                af[i] = *(short8*)&As[(mw + i * 16 + lr) * LDA + h * 32 + lq * 8];
            #pragma unroll
            for (int j = 0; j < 4; j++)
                bf[j] = *(short8*)&Bs[(nw + j * 16 + lr) * LDA + h * 32 + lq * 8];
            #pragma unroll
            for (int i = 0; i < 4; i++)
                #pragma unroll
                for (int j = 0; j < 4; j++)
                    acc[i][j] = __builtin_amdgcn_mfma_f32_16x16x32_bf16(af[i], bf[j], acc[i][j], 0, 0, 0);
        }
        __syncthreads();
    }
    float* S = att + (size_t)batch * C * C;
    #pragma unroll
    for (int i = 0; i < 4; i++)
        #pragma unroll
        for (int j = 0; j < 4; j++)
            #pragma unroll
            for (int r = 0; r < 4; r++) {
                const int row = c0 + mw + i * 16 + lq * 4 + r;
                const int col = d0 + nw + j * 16 + lr;
                unsafeAtomicAdd(&S[(size_t)row * C + col], acc[i][j][r]);
            }
}

__global__ __launch_bounds__(256) void softmax_kernel(float* __restrict__ att) {
    const int C = 512;
    float* S = att + (size_t)blockIdx.x * C;
    const int t = threadIdx.x;
    const float v0 = S[t], v1 = S[t + 256];

    float mn = fminf(v0, v1);
    #pragma unroll
    for (int off = 32; off > 0; off >>= 1) mn = fminf(mn, __shfl_xor(mn, off));
    __shared__ float redmin[4];
    const int wid = t >> 6, lane = t & 63;
    if (lane == 0) redmin[wid] = mn;
    __syncthreads();
    mn = fminf(fminf(redmin[0], redmin[1]), fminf(redmin[2], redmin[3]));

    const float e0 = expf(mn - v0), e1 = expf(mn - v1);
    float s = e0 + e1;
    #pragma unroll
    for (int off = 32; off > 0; off >>= 1) s += __shfl_xor(s, off);
    __shared__ float redsum[4];
    if (lane == 0) redsum[wid] = s;
    __syncthreads();
    s = redsum[0] + redsum[1] + redsum[2] + redsum[3];

    const float inv = 1.0f / s;
    unsigned short* S16 = (unsigned short*)S;
    S16[t] = f2bf(e0 * inv);
    S16[t + 256] = f2bf(e1 * inv);
}

__global__ __launch_bounds__(256, 2) void feat_fb(const float* __restrict__ att,
                                                  const float* __restrict__ x,
                                                  const float* __restrict__ gamma,
                                                  float* __restrict__ out,
                                                  int C, int N) {
    __shared__ short As[GT * LDA];
    __shared__ short Bs[GT * LDA];
    const int b  = blockIdx.z;
    const int c0 = blockIdx.y * GT;
    const int n0 = blockIdx.x * GT;
    const short* Ab = (const short*)(att + (size_t)b * C * C);
    const float* Y = x + (size_t)b * C * N;
    const int t = threadIdx.x;
    const int w = t >> 6, l = t & 63;
    const int mw = (w >> 1) * 64, nw = (w & 1) * 64;
    const int lr = l & 15, lq = l >> 4;

    f32x4 acc[4][4] = {};
    for (int k0 = 0; k0 < C; k0 += BK) {
        #pragma unroll
        for (int i = 0; i < 4; i++) {
            const int v = t + i * 256;
            const int row = v >> 3, q = v & 7;
            uint4 va = *(const uint4*)(Ab + (size_t)(c0 + row) * 1024 + k0 + q * 8);
            *(uint4*)&As[row * LDA + q * 8] = va;
        }
        #pragma unroll
        for (int i = 0; i < 2; i++) {
            const int v = t + i * 256;
            const int kg = v & 15, ng = v >> 4;
            const float* p0 = Y + (size_t)(k0 + kg * 4) * N + n0 + ng * 4;
            float4 r0 = *(const float4*)(p0);
            float4 r1 = *(const float4*)(p0 + N);
            float4 r2 = *(const float4*)(p0 + 2 * (size_t)N);
            float4 r3 = *(const float4*)(p0 + 3 * (size_t)N);
            const float j0[4] = {r0.x, r1.x, r2.x, r3.x};
            const float j1[4] = {r0.y, r1.y, r2.y, r3.y};
            const float j2[4] = {r0.z, r1.z, r2.z, r3.z};
            const float j3[4] = {r0.w, r1.w, r2.w, r3.w};
            const float* cols[4] = {j0, j1, j2, j3};
            #pragma unroll
            for (int j = 0; j < 4; j++) {
                uint2 p = make_uint2(permpack(cols[j][0], cols[j][1]),
                                     permpack(cols[j][2], cols[j][3]));
                *(uint2*)&Bs[(ng * 4 + j) * LDA + kg * 4] = p;
            }
        }
        __syncthreads();
        #pragma unroll
        for (int h = 0; h < 2; h++) {
            short8 af[4], bf[4];
            #pragma unroll
            for (int i = 0; i < 4; i++)
                af[i] = *(short8*)&As[(mw + i * 16 + lr) * LDA + h * 32 + lq * 8];
            #pragma unroll
            for (int j = 0; j < 4; j++)
                bf[j] = *(short8*)&Bs[(nw + j * 16 + lr) * LDA + h * 32 + lq * 8];
            #pragma unroll
            for (int i = 0; i < 4; i++)
                #pragma unroll
                for (int j = 0; j < 4; j++)
                    acc[i][j] = __builtin_amdgcn_mfma_f32_16x16x32_bf16(af[i], bf[j], acc[i][j], 0, 0, 0);
        }
        __syncthreads();
    }

    const float g = gamma[0];
    float* O = out + (size_t)b * C * N;
    const float* X = x + (size_t)b * C * N;
    #pragma unroll
    for (int i = 0; i < 4; i++)
        #pragma unroll
        for (int j = 0; j < 4; j++)
            #pragma unroll
            for (int r = 0; r < 4; r++) {
                const int row = c0 + mw + i * 16 + lq * 4 + r;
                const int col = n0 + nw + j * 16 + lr;
                const size_t idx = (size_t)row * N + col;
                O[idx] = g * acc[i][j][r] + X[idx];
            }
}

extern "C" void kernel_launch(void* const* d_in, const int* in_sizes, int n_in,
                              void* d_out, int out_size, void* d_ws, size_t ws_size,
                              hipStream_t stream) {
    const int B = 8, C = 512, N = 96 * 96;
    const float* x     = (const float*)d_in[0];
    const float* gamma = (const float*)d_in[1];
    float* out = (float*)d_out;
    const size_t attBytes  = (size_t)B * C * C * sizeof(float);           // 8 MB slot
    const size_t ybfBytes  = (size_t)B * C * N * sizeof(short);           // 72 MB
    const size_t partBytes = (size_t)B * NSPLIT * C * C * sizeof(float);  // 64 MB

    dim3 blk(256);
    if (ws_size >= attBytes + ybfBytes + partBytes) {
        // tier-A (144 MB): split-K partials + fused reduce-softmax + feat6
        unsigned short* attbf = (unsigned short*)d_ws;                 // 4 MB used of 8 MB slot
        short* ybf  = (short*)((char*)d_ws + attBytes);
        float* part = (float*)((char*)d_ws + attBytes + ybfBytes);
        tobf16_kernel<<<2048, blk, 0, stream>>>(x, ybf);
        gram_kernel4<<<dim3(8 * NSPLIT * 10), blk, 0, stream>>>(ybf, part);
        rsoftmax_kernel<<<dim3(B * C), blk, 0, stream>>>(part, attbf);
        feat_kernel6<<<dim3(8 * 288), blk, 0, stream>>>((const short*)attbf, ybf, x, gamma, out);
    } else {
        // fallback: fp32-staged verified path (8 MB)
        float* att = (float*)d_ws;
        hipMemsetAsync(att, 0, attBytes, stream);
        gram_fb<<<dim3(C / GT, C / GT, B * FBSPLIT), blk, 0, stream>>>(x, att, C, N);
        softmax_kernel<<<dim3(B * C), blk, 0, stream>>>(att);
        feat_fb<<<dim3(N / GT, C / GT, B), blk, 0, stream>>>(att, x, gamma, out, C, N);
    }
}